// Round 1
// baseline (1678.957 us; speedup 1.0000x reference)
//
#include <hip/hip_runtime.h>
#include <math.h>

#define NN 50000
#define NE 3200000

static constexpr float ACC_SCALE   = 0.005f;
static constexpr float MAX_VEL     = 0.02f;
static constexpr float NOISE_SCALE = 0.004f;
static constexpr float RADIUS      = 0.05f;

// d_out layout (float32, flat concat of reference outputs):
//   [0, 500000)        new_x (N,10)
//   [500000, 550000)   keep_mask (N,) as 0/1
//   550000,550001      velocity_bonus[0,1]
//   550002             border_cost
//   550003             food_reward
//   550004             dead_cost
//   550005             visible_food
//   550006             mean_food_dist
#define OUT_NEWX   0
#define OUT_KEEP   500000
#define OUT_SCAL   550000

// ws layout (float units):
//   [0, 200000)         nodeinfo float4[NN]  (px, py, cell, 0)
//   [200000, 1000000)   s2 float[NN*16]
//   [1000000, 1200000)  oagg float[NN*4]
//   [1200000, 1250000)  degpack int[NN]  (low16 = deg, high16 = consume-deg)
#define WS_NODEINFO 0
#define WS_S2       200000
#define WS_OAGG     1000000
#define WS_DEGPACK  1200000

// ---------------------------------------------------------------------------
// Kernel 1: per-node precompute + zero-init of accumulators.
//   s2[n][j] = b1[j] + cell[n]*W_edge[3][j] + sum_c x[n][c]*W_src[c][j]
// ---------------------------------------------------------------------------
__global__ __launch_bounds__(256) void k1_prep(
    const float* __restrict__ x,
    const float* __restrict__ W_edge,   // (4,16) row-major
    const float* __restrict__ W_src,    // (10,16) row-major
    const float* __restrict__ b1,       // (16,)
    float4* __restrict__ nodeinfo,
    float* __restrict__ s2,
    float4* __restrict__ oagg4,
    int* __restrict__ degpack,
    float* __restrict__ out_scalars)
{
    int n = blockIdx.x * 256 + threadIdx.x;
    if (blockIdx.x == 0 && threadIdx.x < 7) out_scalars[threadIdx.x] = 0.0f;
    if (n >= NN) return;

    float xr[10];
#pragma unroll
    for (int c = 0; c < 10; ++c) xr[c] = x[n * 10 + c];
    float cell = xr[4];

    nodeinfo[n] = make_float4(xr[0], xr[1], cell, 0.0f);

#pragma unroll
    for (int j = 0; j < 16; ++j) {
        float v = fmaf(cell, W_edge[48 + j], b1[j]);
#pragma unroll
        for (int c = 0; c < 10; ++c) v = fmaf(xr[c], W_src[c * 16 + j], v);
        s2[n * 16 + j] = v;
    }

    oagg4[n] = make_float4(0.0f, 0.0f, 0.0f, 0.0f);
    degpack[n] = 0;
}

// ---------------------------------------------------------------------------
// Kernel 2: per-edge.  m = relu(s2[src] + dist*w0 + dx*w1 + dy*w2);
//   oagg[dst] += m @ W_out  (4 atomics instead of 16 — W_out is linear,
//   so it distributes over the segment sum).
// ---------------------------------------------------------------------------
__global__ __launch_bounds__(256) void k2_edge(
    const int* __restrict__ src,
    const int* __restrict__ dst,
    const float* __restrict__ W_edge,   // (4,16)
    const float* __restrict__ W_out,    // (16,4)
    const float4* __restrict__ nodeinfo,
    const float* __restrict__ s2,
    float* __restrict__ oagg,
    int* __restrict__ degpack,
    float* __restrict__ out_scalars)
{
    int e = blockIdx.x * 256 + threadIdx.x;   // grid sized exactly: NE % 256 == 0
    int s = src[e];
    int t = dst[e];

    float4 ns = nodeinfo[s];
    float4 nt = nodeinfo[t];
    float dx = ns.x - nt.x;
    float dy = ns.y - nt.y;
    float dist = sqrtf(fmaf(dx, dx, fmaf(dy, dy, 1e-12f)));
    float food = ns.z;                       // cell[src]

    bool consume = (dist < RADIUS) && (ns.z == 1.0f) && (nt.z == 0.0f);
    atomicAdd(&degpack[t], consume ? (1 | 65536) : 1);

    const float* sv = s2 + (size_t)s * 16;
    float v0 = 0.f, v1 = 0.f, v2 = 0.f, v3 = 0.f;
#pragma unroll
    for (int k = 0; k < 16; ++k) {
        float m = fmaf(dist, W_edge[k],
                  fmaf(dx, W_edge[16 + k],
                  fmaf(dy, W_edge[32 + k], sv[k])));
        m = fmaxf(m, 0.0f);
        v0 = fmaf(m, W_out[k * 4 + 0], v0);
        v1 = fmaf(m, W_out[k * 4 + 1], v1);
        v2 = fmaf(m, W_out[k * 4 + 2], v2);
        v3 = fmaf(m, W_out[k * 4 + 3], v3);
    }
    float* og = oagg + (size_t)t * 4;
    atomicAdd(og + 0, v0);
    atomicAdd(og + 1, v1);
    atomicAdd(og + 2, v2);
    atomicAdd(og + 3, v3);

    // scalar reductions: visible_food (food==0 count), mean_food_dist (sum)
    float vis = (food == 0.0f) ? 1.0f : 0.0f;
    float fd  = (food == 0.0f) ? dist : 0.0f;
#pragma unroll
    for (int off = 32; off > 0; off >>= 1) {
        vis += __shfl_down(vis, off);
        fd  += __shfl_down(fd,  off);
    }
    if ((threadIdx.x & 63) == 0) {
        atomicAdd(&out_scalars[5], vis);
        atomicAdd(&out_scalars[6], fd);
    }
}

// ---------------------------------------------------------------------------
// Kernel 3: per-node update + outputs.
// ---------------------------------------------------------------------------
__global__ __launch_bounds__(256) void k3_node(
    const float* __restrict__ x,
    const float* __restrict__ noise,
    const float* __restrict__ b2,       // (4,)
    const float4* __restrict__ oagg4,
    const int* __restrict__ degpack,
    float* __restrict__ out,
    float* __restrict__ out_scalars)
{
    int n = blockIdx.x * 256 + threadIdx.x;

    float bc = 0.f, avx = 0.f, avy = 0.f, deadf = 0.f, consf = 0.f;

    if (n < NN) {
        float4 o4 = oagg4[n];
        float cell = x[n * 10 + 4];
        float cm = (cell == 1.0f) ? 1.0f : 0.0f;
        float h0 = tanhf(o4.x + b2[0]) * cm;
        float h1 = tanhf(o4.y + b2[1]) * cm;
        float h2 = tanhf(o4.z + b2[2]) * cm;
        float h3 = tanhf(o4.w + b2[3]) * cm;

        float px = x[n * 10 + 0], py = x[n * 10 + 1];
        float vx = x[n * 10 + 2], vy = x[n * 10 + 3];

        float nvx = fminf(fmaxf(fmaf(h0, ACC_SCALE, vx), -MAX_VEL), MAX_VEL);
        float nvy = fminf(fmaxf(fmaf(h1, ACC_SCALE, vy), -MAX_VEL), MAX_VEL);
        float npx = px + nvx;
        float npy = py + nvy;

        float no_x = noise[n * 2 + 0];
        float no_y = noise[n * 2 + 1];
        float vnx = nvx + (no_x * 2.0f - 1.0f) * NOISE_SCALE * cm;
        float vny = nvy + (no_y * 2.0f - 1.0f) * NOISE_SCALE * cm;

        float* row = out + OUT_NEWX + (size_t)n * 10;
        row[0] = npx;  row[1] = npy;
        row[2] = vnx;  row[3] = vny;
        row[4] = cell; row[5] = h2;  row[6] = h3;
        row[7] = x[n * 10 + 7];
        row[8] = x[n * 10 + 8];
        row[9] = x[n * 10 + 9];

        float apx = fabsf(npx), apy = fabsf(npy);
        if (apx > 1.0f) bc += logf(apx + 1e-6f);
        if (apy > 1.0f) bc += logf(apy + 1e-6f);

        int dp = degpack[n];
        int deg  = dp & 0xFFFF;
        int cdeg = dp >> 16;
        bool dead = (cell == 1.0f) && (deg < 3);
        bool cons = (cell == 0.0f) && (cdeg >= 3);
        out[OUT_KEEP + n] = (dead || cons) ? 0.0f : 1.0f;
        deadf = dead ? 1.0f : 0.0f;
        consf = cons ? 1.0f : 0.0f;

        avx = fabsf(nvx) * (1.0f / NN);
        avy = fabsf(nvy) * (1.0f / NN);
    }

#pragma unroll
    for (int off = 32; off > 0; off >>= 1) {
        avx   += __shfl_down(avx,   off);
        avy   += __shfl_down(avy,   off);
        bc    += __shfl_down(bc,    off);
        deadf += __shfl_down(deadf, off);
        consf += __shfl_down(consf, off);
    }
    if ((threadIdx.x & 63) == 0) {
        atomicAdd(&out_scalars[0], avx);
        atomicAdd(&out_scalars[1], avy);
        atomicAdd(&out_scalars[2], bc);
        atomicAdd(&out_scalars[3], consf);  // food_reward = consumed.sum()
        atomicAdd(&out_scalars[4], deadf);  // dead_cost   = dead.sum()
    }
}

extern "C" void kernel_launch(void* const* d_in, const int* in_sizes, int n_in,
                              void* d_out, int out_size, void* d_ws, size_t ws_size,
                              hipStream_t stream) {
    const float* x      = (const float*)d_in[0];
    const int*   src    = (const int*)  d_in[1];
    const int*   dst    = (const int*)  d_in[2];
    const float* noise  = (const float*)d_in[3];
    const float* W_edge = (const float*)d_in[4];
    const float* W_src  = (const float*)d_in[5];
    const float* b1     = (const float*)d_in[6];
    const float* W_out  = (const float*)d_in[7];
    const float* b2     = (const float*)d_in[8];

    float* ws = (float*)d_ws;
    float4* nodeinfo = (float4*)(ws + WS_NODEINFO);
    float*  s2       = ws + WS_S2;
    float*  oagg     = ws + WS_OAGG;
    int*    degpack  = (int*)(ws + WS_DEGPACK);

    float* out         = (float*)d_out;
    float* out_scalars = out + OUT_SCAL;

    k1_prep<<<(NN + 255) / 256, 256, 0, stream>>>(
        x, W_edge, W_src, b1, nodeinfo, s2, (float4*)oagg, degpack, out_scalars);

    k2_edge<<<NE / 256, 256, 0, stream>>>(
        src, dst, W_edge, W_out, nodeinfo, s2, oagg, degpack, out_scalars);

    k3_node<<<(NN + 255) / 256, 256, 0, stream>>>(
        x, noise, b2, (const float4*)oagg, degpack, out, out_scalars);
}

// Round 2
// 245.629 us; speedup vs baseline: 6.8353x; 6.8353x over previous
//
#include <hip/hip_runtime.h>
#include <math.h>

#define NN 50000
#define NE 3200000

#define NTILE 196       // tiles of 256 dst nodes: 196*256 = 50176 >= NN
#define TSZ   256
#define CAP   20480     // bucket capacity per tile (mean 16327, sigma ~128)
#define SCB   250       // scatter blocks
#define SCH   12800     // edges per scatter block: 250*12800 = 3.2M exact

static constexpr float ACC_SCALE   = 0.005f;
static constexpr float MAX_VEL     = 0.02f;
static constexpr float NOISE_SCALE = 0.004f;
static constexpr float RADIUS      = 0.05f;

// d_out layout (float32): new_x[N*10], keep[N], scalars[7]
#define OUT_NEWX   0
#define OUT_KEEP   500000
#define OUT_SCAL   550000
// scalars: 0,1 velocity_bonus; 2 border_cost; 3 food_reward; 4 dead_cost;
//          5 visible_food; 6 mean_food_dist

// ws layout (float units):
#define WS_NI   0          // float4[50176]            -> 200704 floats
#define WS_S2   200704     // float[50176*16]          -> ends 1003520
#define WS_CUR  1003520    // int[NTILE] (+pad to 256)
#define WS_BK   1003776    // uint[NTILE*CAP] = 4014080 -> ends 5017856 (~20 MB)

// ---------------------------------------------------------------------------
// Kernel 1: per-node precompute.
//   s2[n][j] = b1[j] + cell[n]*W_edge[3][j] + sum_c x[n][c]*W_src[c][j]
// Also inits bucket cursors and output scalars.
// ---------------------------------------------------------------------------
__global__ __launch_bounds__(256) void k1_prep(
    const float* __restrict__ x,
    const float* __restrict__ W_edge,   // (4,16)
    const float* __restrict__ W_src,    // (10,16)
    const float* __restrict__ b1,       // (16,)
    float4* __restrict__ nodeinfo,
    float* __restrict__ s2,
    int* __restrict__ cursor,
    float* __restrict__ out_scalars)
{
    int n = blockIdx.x * 256 + threadIdx.x;
    if (blockIdx.x == 0) {
        if (threadIdx.x < 7) out_scalars[threadIdx.x] = 0.0f;
        if (threadIdx.x < NTILE) cursor[threadIdx.x] = threadIdx.x * CAP;
    }
    if (n >= NN) return;

    float xr[10];
#pragma unroll
    for (int c = 0; c < 10; ++c) xr[c] = x[n * 10 + c];
    float cell = xr[4];

    nodeinfo[n] = make_float4(xr[0], xr[1], cell, 0.0f);

#pragma unroll
    for (int j = 0; j < 16; ++j) {
        float v = fmaf(cell, W_edge[48 + j], b1[j]);
#pragma unroll
        for (int c = 0; c < 10; ++c) v = fmaf(xr[c], W_src[c * 16 + j], v);
        s2[n * 16 + j] = v;
    }
}

// ---------------------------------------------------------------------------
// Kernel 2: counting-scatter of edges into per-dst-tile buckets.
// Entry = src (16b) | dst_local (8b) << 16.  One global atomic per
// (block, tile) for space reservation; per-edge positions via LDS atomics.
// ---------------------------------------------------------------------------
__global__ __launch_bounds__(256) void k_scatter(
    const int* __restrict__ src,
    const int* __restrict__ dst,
    int* __restrict__ cursor,
    unsigned* __restrict__ bucket)
{
    __shared__ int hist[NTILE];
    __shared__ int base[NTILE];
    __shared__ int lcur[NTILE];
    int tid = threadIdx.x;
    for (int i = tid; i < NTILE; i += 256) { hist[i] = 0; lcur[i] = 0; }
    __syncthreads();

    int e0 = blockIdx.x * SCH;
#pragma unroll 4
    for (int j = 0; j < SCH / 256; ++j) {
        int d = dst[e0 + j * 256 + tid];
        atomicAdd(&hist[d >> 8], 1);
    }
    __syncthreads();
    for (int i = tid; i < NTILE; i += 256)
        base[i] = atomicAdd(&cursor[i], hist[i]);
    __syncthreads();

    for (int j = 0; j < SCH / 256; ++j) {
        int e = e0 + j * 256 + tid;
        int d = dst[e];
        int s = src[e];
        int b = d >> 8;
        int pos = base[b] + atomicAdd(&lcur[b], 1);
        if (pos < (b + 1) * CAP)   // capacity guard (statistically never hit)
            bucket[pos] = (unsigned)s | ((unsigned)(d & 255) << 16);
    }
}

// ---------------------------------------------------------------------------
// Kernel 3: owner-computes aggregation + node finalize.
// Block t owns dst nodes [t*256, t*256+256): dense loop over its bucket,
// LDS accumulation (no global atomics), then the full node update.
// ---------------------------------------------------------------------------
__global__ __launch_bounds__(512) void k_agg(
    const float* __restrict__ x,
    const float* __restrict__ noise,
    const float* __restrict__ W_edge,   // (4,16)
    const float* __restrict__ W_out,    // (16,4)
    const float* __restrict__ b2,       // (4,)
    const float4* __restrict__ nodeinfo,
    const float* __restrict__ s2,
    const int* __restrict__ cursor,
    const unsigned* __restrict__ bucket,
    float* __restrict__ out,
    float* __restrict__ out_scalars)
{
    __shared__ float  sAcc[TSZ][4];
    __shared__ int    sDeg[TSZ];
    __shared__ float4 sNI[TSZ];
    __shared__ float  sRed[8][8];

    int t = blockIdx.x;
    int tid = threadIdx.x;

    if (tid < TSZ) {
        int g = t * TSZ + tid;
        sNI[tid] = (g < NN) ? nodeinfo[g] : make_float4(9e9f, 9e9f, -1.f, 0.f);
        sAcc[tid][0] = 0.f; sAcc[tid][1] = 0.f;
        sAcc[tid][2] = 0.f; sAcc[tid][3] = 0.f;
        sDeg[tid] = 0;
    }

    // hoist weights into registers
    float w0[16], w1[16], w2[16], woa[16], wob[16], woc[16], wod[16];
#pragma unroll
    for (int k = 0; k < 16; ++k) {
        w0[k] = W_edge[k];
        w1[k] = W_edge[16 + k];
        w2[k] = W_edge[32 + k];
        woa[k] = W_out[k * 4 + 0];
        wob[k] = W_out[k * 4 + 1];
        woc[k] = W_out[k * 4 + 2];
        wod[k] = W_out[k * 4 + 3];
    }
    __syncthreads();

    int cnt = cursor[t] - t * CAP;
    if (cnt > CAP) cnt = CAP;

    float vis = 0.f, fd = 0.f;
    for (int i = tid; i < cnt; i += 512) {
        unsigned e = bucket[t * CAP + i];
        int s  = e & 0xFFFF;
        int dl = (e >> 16) & 0xFF;
        float4 ns = nodeinfo[s];
        float4 nt = sNI[dl];
        float dx = ns.x - nt.x;
        float dy = ns.y - nt.y;
        float dist = sqrtf(fmaf(dx, dx, fmaf(dy, dy, 1e-12f)));

        bool food0 = (ns.z == 0.0f);
        vis += food0 ? 1.f : 0.f;
        fd  += food0 ? dist : 0.f;

        bool consume = (dist < RADIUS) && (ns.z == 1.0f) && (nt.z == 0.0f);
        atomicAdd(&sDeg[dl], consume ? 65537 : 1);

        const float4* sv4 = (const float4*)(s2 + (size_t)s * 16);
        float4 q0 = sv4[0], q1 = sv4[1], q2 = sv4[2], q3 = sv4[3];
        float sv[16] = { q0.x, q0.y, q0.z, q0.w, q1.x, q1.y, q1.z, q1.w,
                         q2.x, q2.y, q2.z, q2.w, q3.x, q3.y, q3.z, q3.w };

        float v0 = 0.f, v1 = 0.f, v2 = 0.f, v3 = 0.f;
#pragma unroll
        for (int k = 0; k < 16; ++k) {
            float m = fmaf(dist, w0[k], fmaf(dx, w1[k], fmaf(dy, w2[k], sv[k])));
            m = fmaxf(m, 0.0f);
            v0 = fmaf(m, woa[k], v0);
            v1 = fmaf(m, wob[k], v1);
            v2 = fmaf(m, woc[k], v2);
            v3 = fmaf(m, wod[k], v3);
        }
        atomicAdd(&sAcc[dl][0], v0);
        atomicAdd(&sAcc[dl][1], v1);
        atomicAdd(&sAcc[dl][2], v2);
        atomicAdd(&sAcc[dl][3], v3);
    }
    __syncthreads();

    // ---- node finalize (old k3) ----
    float avx = 0.f, avy = 0.f, bc = 0.f, deadf = 0.f, consf = 0.f;
    int n = t * TSZ + tid;
    if (tid < TSZ && n < NN) {
        float cell = x[n * 10 + 4];
        float cm = (cell == 1.0f) ? 1.0f : 0.0f;
        float h0 = tanhf(sAcc[tid][0] + b2[0]) * cm;
        float h1 = tanhf(sAcc[tid][1] + b2[1]) * cm;
        float h2 = tanhf(sAcc[tid][2] + b2[2]) * cm;
        float h3 = tanhf(sAcc[tid][3] + b2[3]) * cm;

        float px = x[n * 10 + 0], py = x[n * 10 + 1];
        float vx = x[n * 10 + 2], vy = x[n * 10 + 3];

        float nvx = fminf(fmaxf(fmaf(h0, ACC_SCALE, vx), -MAX_VEL), MAX_VEL);
        float nvy = fminf(fmaxf(fmaf(h1, ACC_SCALE, vy), -MAX_VEL), MAX_VEL);
        float npx = px + nvx;
        float npy = py + nvy;

        float vnx = nvx + (noise[n * 2 + 0] * 2.0f - 1.0f) * NOISE_SCALE * cm;
        float vny = nvy + (noise[n * 2 + 1] * 2.0f - 1.0f) * NOISE_SCALE * cm;

        float* row = out + OUT_NEWX + (size_t)n * 10;
        row[0] = npx;  row[1] = npy;
        row[2] = vnx;  row[3] = vny;
        row[4] = cell; row[5] = h2;  row[6] = h3;
        row[7] = x[n * 10 + 7];
        row[8] = x[n * 10 + 8];
        row[9] = x[n * 10 + 9];

        float apx = fabsf(npx), apy = fabsf(npy);
        if (apx > 1.0f) bc += logf(apx + 1e-6f);
        if (apy > 1.0f) bc += logf(apy + 1e-6f);

        int dp = sDeg[tid];
        int deg  = dp & 0xFFFF;
        int cdeg = dp >> 16;
        bool dead = (cell == 1.0f) && (deg < 3);
        bool cons = (cell == 0.0f) && (cdeg >= 3);
        out[OUT_KEEP + n] = (dead || cons) ? 0.0f : 1.0f;
        deadf = dead ? 1.0f : 0.0f;
        consf = cons ? 1.0f : 0.0f;
        avx = fabsf(nvx) * (1.0f / NN);
        avy = fabsf(nvy) * (1.0f / NN);
    }

    // ---- block-reduce 7 scalars, one atomic each per block ----
    float r[7] = { avx, avy, bc, consf, deadf, vis, fd };
#pragma unroll
    for (int q = 0; q < 7; ++q) {
#pragma unroll
        for (int off = 32; off > 0; off >>= 1)
            r[q] += __shfl_down(r[q], off);
    }
    int lane = tid & 63, wv = tid >> 6;
    if (lane == 0) {
#pragma unroll
        for (int q = 0; q < 7; ++q) sRed[wv][q] = r[q];
    }
    __syncthreads();
    if (tid == 0) {
#pragma unroll
        for (int q = 0; q < 7; ++q) {
            float acc = 0.f;
#pragma unroll
            for (int wq = 0; wq < 8; ++wq) acc += sRed[wq][q];
            atomicAdd(&out_scalars[q], acc);
        }
    }
}

extern "C" void kernel_launch(void* const* d_in, const int* in_sizes, int n_in,
                              void* d_out, int out_size, void* d_ws, size_t ws_size,
                              hipStream_t stream) {
    const float* x      = (const float*)d_in[0];
    const int*   src    = (const int*)  d_in[1];
    const int*   dst    = (const int*)  d_in[2];
    const float* noise  = (const float*)d_in[3];
    const float* W_edge = (const float*)d_in[4];
    const float* W_src  = (const float*)d_in[5];
    const float* b1     = (const float*)d_in[6];
    const float* W_out  = (const float*)d_in[7];
    const float* b2     = (const float*)d_in[8];

    float* ws = (float*)d_ws;
    float4*   nodeinfo = (float4*)(ws + WS_NI);
    float*    s2       = ws + WS_S2;
    int*      cursor   = (int*)(ws + WS_CUR);
    unsigned* bucket   = (unsigned*)(ws + WS_BK);

    float* out         = (float*)d_out;
    float* out_scalars = out + OUT_SCAL;

    k1_prep<<<NTILE, 256, 0, stream>>>(
        x, W_edge, W_src, b1, nodeinfo, s2, cursor, out_scalars);

    k_scatter<<<SCB, 256, 0, stream>>>(src, dst, cursor, bucket);

    k_agg<<<NTILE, 512, 0, stream>>>(
        x, noise, W_edge, W_out, b2, nodeinfo, s2, cursor, bucket,
        out, out_scalars);
}